// Round 1
// baseline (163.944 us; speedup 1.0000x reference)
//
#include <hip/hip_runtime.h>
#include <stdint.h>

#define L_DIM 4096
#define D_DIM 512
#define H_DIM 256
#define T_DIM 8

typedef short bf16x8 __attribute__((ext_vector_type(8)));
typedef float f32x4 __attribute__((ext_vector_type(4)));

// ---------- helpers ----------
__device__ __forceinline__ unsigned short f2bf(float f) {
    union { float f; unsigned int u; } c; c.f = f;
    unsigned int u = c.u;
    unsigned int r = (u + 0x7fffu + ((u >> 16) & 1u)) >> 16;  // RNE
    return (unsigned short)r;
}

__device__ __forceinline__ float wave_sum(float x) {
    #pragma unroll
    for (int off = 32; off > 0; off >>= 1) x += __shfl_xor(x, off, 64);
    return x;
}

__device__ __forceinline__ float dot4(float4 a, float4 b) {
    return a.x * b.x + a.y * b.y + a.z * b.z + a.w * b.w;
}

__device__ __forceinline__ float fast_tanh(float x) {
    float e = __expf(2.0f * x);
    return 1.0f - 2.0f / (e + 1.0f);
}

// ---------- K0: Ws (512x256 f32) -> WsT (256x512 bf16) ----------
__global__ void k_transpose_ws(const float* __restrict__ Ws,
                               unsigned short* __restrict__ WsT) {
    int idx = blockIdx.x * 256 + threadIdx.x;  // 0..131071
    int j = idx >> 9;        // 0..255 (H)
    int k = idx & 511;       // 0..511 (D)
    WsT[idx] = f2bf(Ws[k * H_DIM + j]);        // WsT[j*512+k]
}

// ---------- K1: v = emb @ Ws, bf16 MFMA, M=32768 N=256 K=512 ----------
// BM=128, BN=256, BK=64. 512 threads = 8 waves (2 m-halves x 4 n-quarters).
__global__ __launch_bounds__(512) void k_gemm_v(const float* __restrict__ emb,
                                                const unsigned short* __restrict__ WsT,
                                                float* __restrict__ v) {
    __shared__ __align__(16) char smem[48 * 1024];  // As 16KB @0, Bs 32KB @16KB
    char* As = smem;
    char* Bs = smem + 16 * 1024;

    const int tid  = threadIdx.x;
    const int lane = tid & 63;
    const int wid  = tid >> 6;     // 0..7
    const int wm   = wid & 1;      // m half (64 rows)
    const int wn   = wid >> 1;     // n quarter (64 cols)
    const long rowBase = (long)blockIdx.x * 128;

    f32x4 zero = {0.f, 0.f, 0.f, 0.f};
    f32x4 acc[4][4];
    #pragma unroll
    for (int mi = 0; mi < 4; mi++)
        #pragma unroll
        for (int ni = 0; ni < 4; ni++) acc[mi][ni] = zero;

    for (int kt = 0; kt < 8; ++kt) {
        __syncthreads();
        // stage A: 128 rows x 64 k, f32 -> bf16, XOR-swizzled rows of 128B
        #pragma unroll
        for (int p = 0; p < 4; p++) {
            int g   = p * 512 + tid;     // 0..2047
            int row = g >> 4;            // 0..127
            int q   = g & 15;            // f32-quad within row
            float4 s = *(const float4*)(emb + (rowBase + row) * D_DIM + kt * 64 + q * 4);
            unsigned short b0 = f2bf(s.x), b1 = f2bf(s.y), b2 = f2bf(s.z), b3 = f2bf(s.w);
            uint2 pk;
            pk.x = (unsigned int)b0 | ((unsigned int)b1 << 16);
            pk.y = (unsigned int)b2 | ((unsigned int)b3 << 16);
            *(uint2*)(As + (row * 128 + ((q * 8) ^ ((row & 7) << 4)))) = pk;
        }
        // stage B: 256 j-rows x 64 k bf16 from WsT (already bf16, contiguous in k)
        #pragma unroll
        for (int p = 0; p < 4; p++) {
            int g  = p * 512 + tid;
            int j  = g >> 3;             // 0..255
            int ko = g & 7;              // 16B octet
            uint4 d = *(const uint4*)(WsT + j * D_DIM + kt * 64 + ko * 8);
            *(uint4*)(Bs + (j * 128 + ((ko * 16) ^ ((j & 7) << 4)))) = d;
        }
        __syncthreads();

        #pragma unroll
        for (int ks = 0; ks < 2; ++ks) {
            bf16x8 a[4], b[4];
            #pragma unroll
            for (int mi = 0; mi < 4; mi++) {
                int row = wm * 64 + mi * 16 + (lane & 15);
                a[mi] = *(const bf16x8*)(As + (row * 128 +
                          ((ks * 64 + (lane >> 4) * 16) ^ ((row & 7) << 4))));
            }
            #pragma unroll
            for (int ni = 0; ni < 4; ni++) {
                int j = wn * 64 + ni * 16 + (lane & 15);
                b[ni] = *(const bf16x8*)(Bs + (j * 128 +
                          ((ks * 64 + (lane >> 4) * 16) ^ ((j & 7) << 4))));
            }
            #pragma unroll
            for (int mi = 0; mi < 4; mi++)
                #pragma unroll
                for (int ni = 0; ni < 4; ni++)
                    acc[mi][ni] = __builtin_amdgcn_mfma_f32_16x16x32_bf16(
                        a[mi], b[ni], acc[mi][ni], 0, 0, 0);
        }
    }

    // epilogue: C/D layout col=lane&15, row=(lane>>4)*4+reg  [m89-verified]
    #pragma unroll
    for (int mi = 0; mi < 4; mi++)
        #pragma unroll
        for (int ni = 0; ni < 4; ni++)
            #pragma unroll
            for (int r = 0; r < 4; r++) {
                long row = rowBase + wm * 64 + mi * 16 + (lane >> 4) * 4 + r;
                int  col = wn * 64 + ni * 16 + (lane & 15);
                v[row * H_DIM + col] = acc[mi][ni][r];
            }
}

// ---------- K2: per-row 8-step recurrence, one wave per row ----------
__global__ __launch_bounds__(256) void k_seq(
    const float* __restrict__ emb, const float* __restrict__ rois,
    const float* __restrict__ Wx, const float* __restrict__ bx,
    const float* __restrict__ Wy, const float* __restrict__ by,
    const float* __restrict__ Wz, const float* __restrict__ bz,
    const float* __restrict__ bs, const float* __restrict__ Wh,
    const float* __restrict__ bh, const float* __restrict__ v,
    float* __restrict__ out) {
    const int lane = threadIdx.x & 63;
    const int l = blockIdx.x * 4 + (threadIdx.x >> 6);
    const int j4 = lane * 4;   // H slice (4 per lane)
    const int d8 = lane * 8;   // D slice (8 per lane)

    float4 Wh4 = *(const float4*)(Wh + (long)l * H_DIM + j4);
    float4 bs4 = *(const float4*)(bs + j4);
    float4 wx0 = *(const float4*)(Wx + (long)l * D_DIM + d8);
    float4 wx1 = *(const float4*)(Wx + (long)l * D_DIM + d8 + 4);
    float4 wy0 = *(const float4*)(Wy + (long)l * D_DIM + d8);
    float4 wy1 = *(const float4*)(Wy + (long)l * D_DIM + d8 + 4);
    float4 wz0 = *(const float4*)(Wz + (long)l * D_DIM + d8);
    float4 wz1 = *(const float4*)(Wz + (long)l * D_DIM + d8 + 4);
    float bxl = bx[l], byl = by[l], bzl = bz[l], bhl = bh[l];
    const float sx = 1.f / 767.f, sy = 1.f / 767.f, sz = 1.f / 575.f;

    // ---- t = 0 ----
    float4 e0 = *(const float4*)(emb + (long)l * D_DIM + d8);
    float4 e1 = *(const float4*)(emb + (long)l * D_DIM + d8 + 4);
    float dx = wave_sum(dot4(wx0, e0) + dot4(wx1, e1));
    float dy = wave_sum(dot4(wy0, e0) + dot4(wy1, e1));
    float dz = wave_sum(dot4(wz0, e0) + dot4(wz1, e1));
    float4 u4 = *(const float4*)(v + (long)l * H_DIM + j4);   // u0 = emb0 @ Ws
    float cx = rois[l * 3 + 0], cy = rois[l * 3 + 1], cz = rois[l * 3 + 2];
    float prx = (dx + bxl) * sx + cx;
    float pry = (dy + byl) * sy + cy;
    float prz = (dz + bzl) * sz + cz;
    if (lane == 0) {
        out[l * 3 + 0] = prx; out[l * 3 + 1] = pry; out[l * 3 + 2] = prz;
    }

    // ---- t = 1..7 ----
    for (int t = 1; t < T_DIM; ++t) {
        const float* eb = emb + ((long)t * L_DIM + l) * D_DIM;
        float4 f0 = *(const float4*)(eb + d8);
        float4 f1 = *(const float4*)(eb + d8 + 4);
        float4 v4 = *(const float4*)(v + ((long)t * L_DIM + l) * H_DIM + j4);

        float pxt = wave_sum(dot4(wx0, f0) + dot4(wx1, f1));
        float pyt = wave_sum(dot4(wy0, f0) + dot4(wy1, f1));
        float pzt = wave_sum(dot4(wz0, f0) + dot4(wz1, f1));

        float4 sf, sa;
        sf.x = fast_tanh(u4.x + bs4.x); sf.y = fast_tanh(u4.y + bs4.y);
        sf.z = fast_tanh(u4.z + bs4.z); sf.w = fast_tanh(u4.w + bs4.w);
        sa.x = fast_tanh(v4.x + bs4.x); sa.y = fast_tanh(v4.y + bs4.y);
        sa.z = fast_tanh(v4.z + bs4.z); sa.w = fast_tanh(v4.w + bs4.w);
        float gf = wave_sum(dot4(Wh4, sf)) + bhl;
        float ga = wave_sum(dot4(Wh4, sa)) + bhl;

        // softmax([gf,ga]) == (sigmoid(gf-ga), sigmoid(ga-gf))
        float g0 = 1.0f / (1.0f + __expf(ga - gf));
        float g1 = 1.0f - g0;

        u4.x = g0 * u4.x + g1 * v4.x; u4.y = g0 * u4.y + g1 * v4.y;
        u4.z = g0 * u4.z + g1 * v4.z; u4.w = g0 * u4.w + g1 * v4.w;

        // c uses OLD pred (rois = pred_{t-1}) — before pred is overwritten
        cx = cx * g0 + prx * g1; cy = cy * g0 + pry * g1; cz = cz * g0 + prz * g1;
        dx = g0 * dx + g1 * pxt; dy = g0 * dy + g1 * pyt; dz = g0 * dz + g1 * pzt;

        prx = (dx + bxl) * sx + cx;
        pry = (dy + byl) * sy + cy;
        prz = (dz + bzl) * sz + cz;
        if (lane == 0) {
            float* o = out + (long)t * (L_DIM * 3) + l * 3;
            o[0] = prx; o[1] = pry; o[2] = prz;
        }
    }
}

// ---------- launch ----------
extern "C" void kernel_launch(void* const* d_in, const int* in_sizes, int n_in,
                              void* d_out, int out_size, void* d_ws, size_t ws_size,
                              hipStream_t stream) {
    const float* emb  = (const float*)d_in[0];
    const float* rois = (const float*)d_in[1];
    const float* Wx   = (const float*)d_in[2];
    const float* bx   = (const float*)d_in[3];
    const float* Wy   = (const float*)d_in[4];
    const float* by   = (const float*)d_in[5];
    const float* Wz   = (const float*)d_in[6];
    const float* bz   = (const float*)d_in[7];
    const float* Ws   = (const float*)d_in[8];
    const float* bs   = (const float*)d_in[9];
    const float* Wh   = (const float*)d_in[10];
    const float* bh   = (const float*)d_in[11];
    float* out = (float*)d_out;

    // workspace: v (32768x256 f32 = 32MB) @0, WsT (256x512 bf16 = 256KB) after
    float* v = (float*)d_ws;
    unsigned short* WsT = (unsigned short*)((char*)d_ws + (size_t)32768 * 256 * 4);

    hipLaunchKernelGGL(k_transpose_ws, dim3(512), dim3(256), 0, stream, Ws, WsT);
    hipLaunchKernelGGL(k_gemm_v, dim3(256), dim3(512), 0, stream, emb, WsT, v);
    hipLaunchKernelGGL(k_seq, dim3(1024), dim3(256), 0, stream,
                       emb, rois, Wx, bx, Wy, by, Wz, bz, bs, Wh, bh, v, out);
}